// Round 7
// baseline (1840.922 us; speedup 1.0000x reference)
//
#include <hip/hip_runtime.h>
#include <math.h>

#define NN 50000
#define NE 200000
#define NH 4
#define NG 100
#define EPSBN 1e-5f
#define SLOPE 0.2f

typedef __attribute__((ext_vector_type(8))) short bf16x8;
typedef __attribute__((ext_vector_type(4))) float f32x4;

union U8 { bf16x8 v; uint4 q; unsigned w[4]; };

__device__ __forceinline__ unsigned short f2bf(float f) {
    unsigned u = __float_as_uint(f);
    unsigned r = (u + 0x7fffu + ((u >> 16) & 1u)) >> 16;   // RNE
    return (unsigned short)r;
}
__device__ __forceinline__ float bf2f(unsigned short s) {
    return __uint_as_float(((unsigned)s) << 16);
}

__global__ void fill_val(float* p, int n, float v) {
    int i = blockIdx.x * 256 + threadIdx.x;
    if (i < n) p[i] = v;
}

// ================= weight prep: fragment-tiled split panels =================
// Tiled layout per (512-col x 256-k) head panel: tile = n>>4 (32 tiles), kt = k>>5
// (8 ktiles); short idx = h*131072 + (tile*8 + kt)*512 + (((k>>3)&3)*16 + (n&15))*8 + (k&7).
// By construction: GEMM lane l reads shorts [l*8, l*8+8) of (tile,kt) -> coalesced.
__device__ __forceinline__ size_t tiled_idx(int h, int n, int k) {
    return (size_t)h * 131072 + (((size_t)(n >> 4) * 8 + (k >> 5)) << 9)
         + ((((k >> 3) & 3) << 4) + (n & 15)) * 8 + (k & 7);
}

// L1: element (h, n, k) = (n<256 ? Wl1 : Wr1)[k][h*256 + (n&255)];  W1 is [256,1024]
__global__ void wprep1t(const float* __restrict__ Wl, const float* __restrict__ Wr,
                        unsigned short* __restrict__ Bh, unsigned short* __restrict__ Bl) {
    int idx = blockIdx.x * 256 + threadIdx.x;   // 4*512*256 = 524288
    int n = idx & 511, k = (idx >> 9) & 255, h = idx >> 17;
    const float* W = (n < 256) ? Wl : Wr;
    float w = W[(size_t)k * 1024 + h * 256 + (n & 255)];
    size_t dst = tiled_idx(h, n, k);
    unsigned u = __float_as_uint(w);
    Bh[dst] = (unsigned short)(u >> 16);                       // trunc hi (exact)
    Bl[dst] = f2bf(w - __uint_as_float(u & 0xFFFF0000u));      // RNE lo
}
// L2: element (h, n, k) = (n<256 ? Wl2 : Wr2)[h*256 + k][n&255];  W2 is [1024,256]
__global__ void wprep2t(const float* __restrict__ Wl, const float* __restrict__ Wr,
                        unsigned short* __restrict__ Bh, unsigned short* __restrict__ Bl) {
    int idx = blockIdx.x * 256 + threadIdx.x;
    int n = idx & 511, k = (idx >> 9) & 255, h = idx >> 17;
    const float* W = (n < 256) ? Wl : Wr;
    float w = W[(size_t)(h * 256 + k) * 256 + (n & 255)];
    size_t dst = tiled_idx(h, n, k);
    unsigned u = __float_as_uint(w);
    Bh[dst] = (unsigned short)(u >> 16);
    Bl[dst] = f2bf(w - __uint_as_float(u & 0xFFFF0000u));
}

// ================= LDS-free split-bf16 MFMA GEMM =================
// C[M,512] = A[M,256] @ B[512,256]^T (+bias / +=). 256 thr = 4 waves; wave w owns
// rows [m0+32w, +32) x all 128 cols of its col-block. Frags loaded straight from
// global (coalesced lane*16B via tiled layout); A split in-reg when AF32.
// 3 MFMA passes: Ah*Bh + Al*Bh + Ah*Bl.  No LDS, no barriers.
// grid (4, 391): consecutive blocks share the A row-strip (L2/L3 reuse).
template<bool AF32>   // AF32: L1 (A = raw x f32, C = xl|xr planes). else: L2 (A = tiled h1 region, C = xlr2 += )
__launch_bounds__(256, 3)
__global__ void gemm_tiled(const float* __restrict__ Axf,
                           const unsigned short* __restrict__ Atile,
                           const unsigned short* __restrict__ Bh,
                           const unsigned short* __restrict__ Bl,
                           const float* __restrict__ bL, const float* __restrict__ bR,
                           float* __restrict__ C0, float* __restrict__ C1,
                           int M, int accum) {
    const int lane = threadIdx.x & 63, wid = threadIdx.x >> 6;
    const int n0 = blockIdx.x * 128;
    const int m0 = blockIdx.y * 128;
    const int r15 = lane & 15, kq = lane >> 4;

    f32x4 acc[2][8];
#pragma unroll
    for (int m = 0; m < 2; ++m)
#pragma unroll
        for (int n = 0; n < 8; ++n) acc[m][n] = (f32x4){0.f, 0.f, 0.f, 0.f};

    for (int kt = 0; kt < 8; ++kt) {
        bf16x8 ah[2], al[2];
        if (AF32) {
#pragma unroll
            for (int m = 0; m < 2; ++m) {
                int row = m0 + wid * 32 + m * 16 + r15;
                row = row < M ? row : M - 1;   // clamp: OOB rows only feed discarded C rows
                const float* xp = Axf + (size_t)row * 256 + kt * 32 + kq * 8;
                float4 v0 = *(const float4*)xp;
                float4 v1 = *(const float4*)(xp + 4);
                float vv[8];
                *(float4*)&vv[0] = v0; *(float4*)&vv[4] = v1;
                U8 uh, ul;
#pragma unroll
                for (int j = 0; j < 4; ++j) {
                    float a0 = vv[2 * j], a1 = vv[2 * j + 1];
                    unsigned u0 = __float_as_uint(a0), u1 = __float_as_uint(a1);
                    uh.w[j] = (u0 >> 16) | (u1 & 0xFFFF0000u);   // trunc hi pair
                    float l0 = a0 - __uint_as_float(u0 & 0xFFFF0000u);
                    float l1 = a1 - __uint_as_float(u1 & 0xFFFF0000u);
                    ul.w[j] = (unsigned)f2bf(l0) | ((unsigned)f2bf(l1) << 16);
                }
                ah[m] = uh.v; al[m] = ul.v;
            }
        } else {
#pragma unroll
            for (int m = 0; m < 2; ++m) {
                size_t t = (size_t)(m0 >> 4) + wid * 2 + m;   // 16-row tile index
                const unsigned short* ap = Atile + t * 8192 + kt * 512 + lane * 8;
                ah[m] = *(const bf16x8*)ap;
                al[m] = *(const bf16x8*)(ap + 4096);
            }
        }
#pragma unroll
        for (int g = 0; g < 2; ++g) {
            bf16x8 bh[4], blo[4];
#pragma unroll
            for (int n = 0; n < 4; ++n) {
                size_t nt = (size_t)blockIdx.x * 8 + g * 4 + n;
                const unsigned short* bp = Bh + ((nt * 8 + kt) << 9) + lane * 8;
                const unsigned short* bq = Bl + ((nt * 8 + kt) << 9) + lane * 8;
                bh[n] = *(const bf16x8*)bp;
                blo[n] = *(const bf16x8*)bq;
            }
#pragma unroll
            for (int m = 0; m < 2; ++m)
#pragma unroll
                for (int n = 0; n < 4; ++n) {
                    acc[m][g * 4 + n] = __builtin_amdgcn_mfma_f32_16x16x32_bf16(
                        ah[m], bh[n], acc[m][g * 4 + n], 0, 0, 0);
                    acc[m][g * 4 + n] = __builtin_amdgcn_mfma_f32_16x16x32_bf16(
                        al[m], bh[n], acc[m][g * 4 + n], 0, 0, 0);
                    acc[m][g * 4 + n] = __builtin_amdgcn_mfma_f32_16x16x32_bf16(
                        ah[m], blo[n], acc[m][g * 4 + n], 0, 0, 0);
                }
        }
    }
    // ---- epilogue ----
#pragma unroll
    for (int nf = 0; nf < 8; ++nf) {
        int gcol = n0 + nf * 16 + r15;
        if (AF32) {   // split output planes (xl | xr)
            float* P = (gcol < 256) ? C0 : C1;
            int col = gcol & 255;
            float bv = (gcol < 256) ? bL[col] : bR[col];
#pragma unroll
            for (int m = 0; m < 2; ++m)
#pragma unroll
                for (int r = 0; r < 4; ++r) {
                    int grow = m0 + wid * 32 + m * 16 + kq * 4 + r;
                    if (grow < M) P[(size_t)grow * 256 + col] = acc[m][nf][r] + bv;
                }
        } else {      // interleaved xlr2, optional accumulate
            float bv = accum ? 0.f : (gcol < 256 ? bL[gcol] : bR[gcol - 256]);
#pragma unroll
            for (int m = 0; m < 2; ++m)
#pragma unroll
                for (int r = 0; r < 4; ++r) {
                    int grow = m0 + wid * 32 + m * 16 + kq * 4 + r;
                    if (grow < M) {
                        size_t o = (size_t)grow * 512 + gcol;
                        C0[o] = (accum ? C0[o] : 0.f) + acc[m][nf][r] + bv;
                    }
                }
        }
    }
}

// ================= CSR build over dst (verified round 5/6) =================
__global__ void csr_count(const int* __restrict__ ei, int* __restrict__ cnt) {
    int e = blockIdx.x * 256 + threadIdx.x;
    if (e < NE) atomicAdd(&cnt[ei[NE + e]], 1);
}
__launch_bounds__(1024)
__global__ void csr_offsets(const int* __restrict__ cnt, int* __restrict__ off,
                            int* __restrict__ cursor) {
    __shared__ int s[1024];
    const int t = threadIdx.x;
    const int PER = 49;
    const int base = t * PER;
    int sum = 0;
    for (int i = 0; i < PER; ++i) {
        int idx = base + i;
        if (idx < NN) sum += cnt[idx];
    }
    s[t] = sum;
    __syncthreads();
    for (int d = 1; d < 1024; d <<= 1) {
        int v = (t >= d) ? s[t - d] : 0;
        __syncthreads();
        s[t] += v;
        __syncthreads();
    }
    int run = s[t] - sum;
    for (int i = 0; i < PER; ++i) {
        int idx = base + i;
        if (idx < NN) {
            off[idx] = run;
            cursor[idx] = run;
            run += cnt[idx];
            if (idx == NN - 1) off[NN] = run;
        }
    }
}
__global__ void csr_fill(const int* __restrict__ ei, int* __restrict__ cursor,
                         int* __restrict__ eidl) {
    int e = blockIdx.x * 256 + threadIdx.x;
    if (e < NE) {
        int d = ei[NE + e];
        int p = atomicAdd(&cursor[d], 1);
        eidl[p] = e;
    }
}

// ---------- per-edge logit partial (4 channels/lane, register We) ----------
__device__ __forceinline__ float edge_part(const float4& l, const float4& r,
                                           const float* ev, const float (*rW)[4],
                                           const float4& attv) {
    const float* lp = &l.x; const float* rp = &r.x; const float* ap = &attv.x;
    float part = 0.f;
#pragma unroll
    for (int j = 0; j < 4; ++j) {
        float ecf = 0.f;
#pragma unroll
        for (int d = 0; d < 12; ++d) ecf = fmaf(ev[d], rW[d][j], ecf);
        float mv = lp[j] + rp[j] + ecf;
        mv = mv > 0.f ? mv : SLOPE * mv;
        part = fmaf(mv, ap[j], part);
    }
    return part;
}

// ================= node pass L1: softmax-agg + bias/relu/bn -> tiled split h1 =================
// 1024 thr = 16 waves = 16 nodes (one 16-row tile). xr plane read pre-barrier;
// h1 hi/lo written post-barrier into the SAME region (tile t <-> rows 16t..16t+15).
__launch_bounds__(1024)
__global__ void node_l1(const float* __restrict__ xl, float* __restrict__ region,
                        const int* __restrict__ off, const int* __restrict__ eidl,
                        const int* __restrict__ ei, const float* __restrict__ ea,
                        const float* __restrict__ We, const float* __restrict__ att,
                        const float* __restrict__ bias, const float* __restrict__ gam,
                        const float* __restrict__ bet, const float* __restrict__ mu,
                        const float* __restrict__ var) {
    const int n = blockIdx.x * 16 + (threadIdx.x >> 6);
    const int lane = threadIdx.x & 63;
    const int cf = lane * 4;
    float rW[12][4];
#pragma unroll
    for (int d = 0; d < 12; ++d) {
        float4 w = *(const float4*)&We[(size_t)d * 1024 + cf];
        rW[d][0] = w.x; rW[d][1] = w.y; rW[d][2] = w.z; rW[d][3] = w.w;
    }
    const float4 attv = *(const float4*)&att[cf];
    const float4 xr4 = *(const float4*)((const char*)region + (size_t)n * 1024 + cf * 4);
    __syncthreads();   // all xr reads of this 16-row tile complete before any write

    float acc[4] = {0.f, 0.f, 0.f, 0.f};
    float den = 0.f;
    const int beg = off[n], end = off[n + 1];
    int k = beg;
    for (; k + 2 <= end; k += 2) {
        int e0 = eidl[k], e1 = eidl[k + 1];
        int s0 = ei[e0], s1 = ei[e1];
        float ev0[12], ev1[12];
        const float2* p0 = (const float2*)(ea + (size_t)e0 * 12);
        const float2* p1 = (const float2*)(ea + (size_t)e1 * 12);
#pragma unroll
        for (int d = 0; d < 6; ++d) {
            float2 a = p0[d], b = p1[d];
            ev0[2 * d] = a.x; ev0[2 * d + 1] = a.y;
            ev1[2 * d] = b.x; ev1[2 * d + 1] = b.y;
        }
        float4 l0 = *(const float4*)(xl + (size_t)s0 * 256 + cf);
        float4 l1 = *(const float4*)(xl + (size_t)s1 * 256 + cf);
        float pa = edge_part(l0, xr4, ev0, rW, attv);
        float pb = edge_part(l1, xr4, ev1, rW, attv);
#pragma unroll
        for (int o = 32; o > 0; o >>= 1) {
            pa += __shfl_xor(pa, o);
            pb += __shfl_xor(pb, o);
        }
        float ex0 = __expf(pa), ex1 = __expf(pb);
        den += ex0 + ex1;
        const float* lp0 = &l0.x; const float* lp1 = &l1.x;
#pragma unroll
        for (int j = 0; j < 4; ++j)
            acc[j] = fmaf(ex0, lp0[j], fmaf(ex1, lp1[j], acc[j]));
    }
    if (k < end) {
        int e0 = eidl[k];
        int s0 = ei[e0];
        float ev0[12];
        const float2* p0 = (const float2*)(ea + (size_t)e0 * 12);
#pragma unroll
        for (int d = 0; d < 6; ++d) {
            float2 a = p0[d];
            ev0[2 * d] = a.x; ev0[2 * d + 1] = a.y;
        }
        float4 l0 = *(const float4*)(xl + (size_t)s0 * 256 + cf);
        float pa = edge_part(l0, xr4, ev0, rW, attv);
#pragma unroll
        for (int o = 32; o > 0; o >>= 1) pa += __shfl_xor(pa, o);
        float ex0 = __expf(pa);
        den += ex0;
        const float* lp0 = &l0.x;
#pragma unroll
        for (int j = 0; j < 4; ++j) acc[j] = fmaf(ex0, lp0[j], acc[j]);
    }
    const float inv = 1.f / (den + 1e-16f);
    ushort4 hv, lv;
    unsigned short* hp = &hv.x; unsigned short* lp = &lv.x;
#pragma unroll
    for (int j = 0; j < 4; ++j) {
        int c = cf + j;
        float t = fmaxf(acc[j] * inv + bias[c], 0.f);
        float o = (t - mu[c]) * rsqrtf(var[c] + EPSBN) * gam[c] + bet[c];
        unsigned u = __float_as_uint(o);
        hp[j] = (unsigned short)(u >> 16);
        lp[j] = f2bf(o - __uint_as_float(u & 0xFFFF0000u));
    }
    unsigned short* H = (unsigned short*)region;
    size_t idx = (size_t)(n >> 4) * 8192 + (cf >> 5) * 512
               + ((((cf >> 3) & 3) << 4) + (n & 15)) * 8 + (cf & 7);
    *(ushort4*)(H + idx) = hv;
    *(ushort4*)(H + idx + 4096) = lv;
}

// ================= node pass L2 (4 heads, xlr2 interleaved, f32 in-place) =================
__launch_bounds__(256)
__global__ void node_l2(float* __restrict__ xlr,
                        const int* __restrict__ off, const int* __restrict__ eidl,
                        const int* __restrict__ ei, const float* __restrict__ ea,
                        const float* __restrict__ We, const float* __restrict__ att,
                        const float* __restrict__ bias, const float* __restrict__ gam,
                        const float* __restrict__ bet, const float* __restrict__ mu,
                        const float* __restrict__ var) {
    const int n = blockIdx.x * 4 + (threadIdx.x >> 6);
    const int lane = threadIdx.x & 63;
    const int cf = lane * 4;
    float rW[12][4];
#pragma unroll
    for (int d = 0; d < 12; ++d) {
        float4 w = *(const float4*)&We[(size_t)d * 256 + cf];
        rW[d][0] = w.x; rW[d][1] = w.y; rW[d][2] = w.z; rW[d][3] = w.w;
    }
    const float4 attv = *(const float4*)&att[cf];
    float* xrow = xlr + (size_t)n * 512;
    const float4 xr4 = *(const float4*)(xrow + 256 + cf);
    float acc[4] = {0.f, 0.f, 0.f, 0.f};
    float den = 0.f;
    const int beg = off[n], end = off[n + 1];
    int k = beg;
    for (; k + 2 <= end; k += 2) {
        int e0 = eidl[k], e1 = eidl[k + 1];
        int s0 = ei[e0], s1 = ei[e1];
        float ev0[12], ev1[12];
        const float2* p0 = (const float2*)(ea + (size_t)e0 * 12);
        const float2* p1 = (const float2*)(ea + (size_t)e1 * 12);
#pragma unroll
        for (int d = 0; d < 6; ++d) {
            float2 a = p0[d], b = p1[d];
            ev0[2 * d] = a.x; ev0[2 * d + 1] = a.y;
            ev1[2 * d] = b.x; ev1[2 * d + 1] = b.y;
        }
        float4 l0 = *(const float4*)(xlr + (size_t)s0 * 512 + cf);
        float4 l1 = *(const float4*)(xlr + (size_t)s1 * 512 + cf);
        float pa = edge_part(l0, xr4, ev0, rW, attv);
        float pb = edge_part(l1, xr4, ev1, rW, attv);
#pragma unroll
        for (int o = 8; o > 0; o >>= 1) {   // RED=16 (4 heads)
            pa += __shfl_xor(pa, o);
            pb += __shfl_xor(pb, o);
        }
        float ex0 = __expf(pa), ex1 = __expf(pb);
        den += ex0 + ex1;
        const float* lp0 = &l0.x; const float* lp1 = &l1.x;
#pragma unroll
        for (int j = 0; j < 4; ++j)
            acc[j] = fmaf(ex0, lp0[j], fmaf(ex1, lp1[j], acc[j]));
    }
    if (k < end) {
        int e0 = eidl[k];
        int s0 = ei[e0];
        float ev0[12];
        const float2* p0 = (const float2*)(ea + (size_t)e0 * 12);
#pragma unroll
        for (int d = 0; d < 6; ++d) {
            float2 a = p0[d];
            ev0[2 * d] = a.x; ev0[2 * d + 1] = a.y;
        }
        float4 l0 = *(const float4*)(xlr + (size_t)s0 * 512 + cf);
        float pa = edge_part(l0, xr4, ev0, rW, attv);
#pragma unroll
        for (int o = 8; o > 0; o >>= 1) pa += __shfl_xor(pa, o);
        float ex0 = __expf(pa);
        den += ex0;
        const float* lp0 = &l0.x;
#pragma unroll
        for (int j = 0; j < 4; ++j) acc[j] = fmaf(ex0, lp0[j], acc[j]);
    }
    const float inv = 1.f / (den + 1e-16f);
    float o[4];
#pragma unroll
    for (int j = 0; j < 4; ++j) {
        int c = cf + j;
        float t = fmaxf(acc[j] * inv + bias[c], 0.f);
        o[j] = (t - mu[c]) * rsqrtf(var[c] + EPSBN) * gam[c] + bet[c];
    }
    *(float4*)(xrow + 256 + cf) = make_float4(o[0], o[1], o[2], o[3]);
}

// ================= head MLP =================
__launch_bounds__(64)
__global__ void head_mlp(const float* __restrict__ h2, const int* __restrict__ n_nodes,
                         const float* __restrict__ Wf1, const float* __restrict__ bf1,
                         const float* __restrict__ Wf2, const float* __restrict__ bf2,
                         float* __restrict__ out) {
    const int g = blockIdx.x;
    const int t = threadIdx.x;
    int acc = 0;
    for (int i = t; i <= g; i += 64) acc += n_nodes[i];
#pragma unroll
    for (int off = 32; off > 0; off >>= 1) acc += __shfl_xor(acc, off);
    const int node = acc - 1;
    __shared__ float row[256];
    for (int i = t; i < 256; i += 64) row[i] = h2[(size_t)node * 512 + 256 + i];
    __syncthreads();
    float hid = bf1[t];
    for (int k = 0; k < 256; ++k) hid = fmaf(row[k], Wf1[k * 64 + t], hid);
    hid = fmaxf(hid, 0.f);
    float p = hid * Wf2[t];
#pragma unroll
    for (int off = 32; off > 0; off >>= 1) p += __shfl_xor(p, off);
    if (t == 0) out[g] = p + bf2[0];
}

extern "C" void kernel_launch(void* const* d_in, const int* in_sizes, int n_in,
                              void* d_out, int out_size, void* d_ws, size_t ws_size,
                              hipStream_t stream) {
    const float* x   = (const float*)d_in[0];
    const int*   ei  = (const int*)d_in[1];
    const float* ea  = (const float*)d_in[2];
    const int*   nnd = (const int*)d_in[3];
    const float* Wl1 = (const float*)d_in[4];
    const float* bl1 = (const float*)d_in[5];
    const float* Wr1 = (const float*)d_in[6];
    const float* br1 = (const float*)d_in[7];
    const float* We1 = (const float*)d_in[8];
    const float* att1= (const float*)d_in[9];
    const float* b1  = (const float*)d_in[10];
    const float* g1  = (const float*)d_in[11];
    const float* be1 = (const float*)d_in[12];
    const float* m1  = (const float*)d_in[13];
    const float* v1  = (const float*)d_in[14];
    const float* Wl2 = (const float*)d_in[15];
    const float* bl2 = (const float*)d_in[16];
    const float* Wr2 = (const float*)d_in[17];
    const float* br2 = (const float*)d_in[18];
    const float* We2 = (const float*)d_in[19];
    const float* att2= (const float*)d_in[20];
    const float* b2  = (const float*)d_in[21];
    const float* g2  = (const float*)d_in[22];
    const float* be2 = (const float*)d_in[23];
    const float* m2  = (const float*)d_in[24];
    const float* v2  = (const float*)d_in[25];
    const float* Wf1 = (const float*)d_in[26];
    const float* bf1 = (const float*)d_in[27];
    const float* Wf2 = (const float*)d_in[28];
    const float* bf2 = (const float*)d_in[29];
    float* out = (float*)d_out;

    // ---- workspace layout (~210.4 MB; proven >= 213.0 MB available) ----
    const size_t XLB = (size_t)NN * 256 * 4;            // 51.2 MB  xl plane
    const size_t RGB = (size_t)3128 * 16384;            // 51.25 MB xr plane / tiled h1
    const size_t X2B = (size_t)NN * 512 * 4;            // 102.4 MB xlr2
    const size_t WPB = (size_t)4 * 512 * 256 * 2;       // 1 MB per split plane
    char* ws = (char*)d_ws;
    size_t off = 0;
    float* xl_p   = (float*)(ws + off); off += XLB;
    char*  region = (ws + off);         off += RGB;     // xr f32 rows / h1 hi|lo tiles
    float* xlr2   = (float*)(ws + off); off += X2B;
    unsigned short* B1h = (unsigned short*)(ws + off); off += WPB;
    unsigned short* B1l = (unsigned short*)(ws + off); off += WPB;
    unsigned short* B2h = (unsigned short*)(ws + off); off += WPB;
    unsigned short* B2l = (unsigned short*)(ws + off); off += WPB;
    int* cnt    = (int*)(ws + off); off += (size_t)NN * 4;
    int* csroff = (int*)(ws + off); off += ((size_t)(NN + 1) * 4 + 15) & ~15ull;
    int* cursor = (int*)(ws + off); off += (size_t)NN * 4;
    int* eidl   = (int*)(ws + off); off += (size_t)NE * 4;
    if (ws_size < off) {
        fill_val<<<(out_size + 255) / 256, 256, 0, stream>>>(out, out_size, 1e30f);
        return;
    }

    // ---- CSR build (once) ----
    hipMemsetAsync(cnt, 0, (size_t)NN * 4, stream);
    csr_count<<<(NE + 255) / 256, 256, 0, stream>>>(ei, cnt);
    csr_offsets<<<1, 1024, 0, stream>>>(cnt, csroff, cursor);
    csr_fill<<<(NE + 255) / 256, 256, 0, stream>>>(ei, cursor, eidl);

    // ---- weight prep + h1 pad-tile zero (rows 50000..50047) ----
    wprep1t<<<2048, 256, 0, stream>>>(Wl1, Wr1, B1h, B1l);
    wprep2t<<<2048, 256, 0, stream>>>(Wl2, Wr2, B2h, B2l);
    hipMemsetAsync(region + (size_t)3125 * 16384, 0, (size_t)3 * 16384, stream);

    const dim3 gg(4, (NN + 127) / 128);   // 4 col-blocks x 391 row-strips

    for (int h = 0; h < NH; ++h) {
        // [xl | xr] = x @ [Wl1_h | Wr1_h] + bias   (LDS-free MFMA, split planes out)
        gemm_tiled<true><<<gg, 256, 0, stream>>>(
            x, nullptr, B1h + (size_t)h * 131072, B1l + (size_t)h * 131072,
            bl1 + h * 256, br1 + h * 256, xl_p, (float*)region, NN, 0);
        // softmax-aggregate + bias/relu/bn -> h1_h tiled hi/lo over xr region
        node_l1<<<NN / 16, 1024, 0, stream>>>(
            xl_p, (float*)region, csroff, eidl, ei, ea, We1 + h * 256, att1 + h * 256,
            b1 + h * 256, g1 + h * 256, be1 + h * 256, m1 + h * 256, v1 + h * 256);
        // xlr2 (+)= h1_h @ [Wl2_chunk | Wr2_chunk]
        gemm_tiled<false><<<gg, 256, 0, stream>>>(
            nullptr, (const unsigned short*)region, B2h + (size_t)h * 131072,
            B2l + (size_t)h * 131072, bl2, br2, xlr2, nullptr, NN, h > 0 ? 1 : 0);
    }

    // layer-2 attention (4 heads), f32 in-place over xr half of xlr2
    node_l2<<<NN / 4, 256, 0, stream>>>(
        xlr2, csroff, eidl, ei, ea, We2, att2, b2, g2, be2, m2, v2);

    head_mlp<<<NG, 64, 0, stream>>>(xlr2, nnd, Wf1, bf1, Wf2, bf2, out);
}

// Round 8
// 1628.027 us; speedup vs baseline: 1.1308x; 1.1308x over previous
//
#include <hip/hip_runtime.h>
#include <math.h>

#define NN 50000
#define NE 200000
#define NH 4
#define NG 100
#define EPSBN 1e-5f
#define SLOPE 0.2f

typedef __attribute__((ext_vector_type(8))) short bf16x8;
typedef __attribute__((ext_vector_type(4))) float f32x4;

union U8 { bf16x8 v; uint4 q; unsigned w[4]; };

__device__ __forceinline__ unsigned short f2bf(float f) {
    unsigned u = __float_as_uint(f);
    unsigned r = (u + 0x7fffu + ((u >> 16) & 1u)) >> 16;   // RNE
    return (unsigned short)r;
}
__device__ __forceinline__ float bf2f(unsigned short s) {
    return __uint_as_float(((unsigned)s) << 16);
}

__global__ void fill_val(float* p, int n, float v) {
    int i = blockIdx.x * 256 + threadIdx.x;
    if (i < n) p[i] = v;
}

// ================= weight prep: fragment-tiled split panels =================
// short idx per head-panel: ((n>>4)*8 + (k>>5))*512 + (((k>>3)&3)*16 + (n&15))*8 + (k&7)
// => GEMM lane l reads shorts [l*8, l*8+8) of tile (nt,kt): coalesced; and each
// 64-col slice s occupies shorts [s*16384, +16384): contiguous for linear LDS fill.
__device__ __forceinline__ size_t tiled_idx(int h, int n, int k) {
    return (size_t)h * 131072 + (((size_t)(n >> 4) * 8 + (k >> 5)) << 9)
         + ((((k >> 3) & 3) << 4) + (n & 15)) * 8 + (k & 7);
}

// L1: element (h,n,k) = (n<256 ? Wl1 : Wr1)[k][h*256 + (n&255)];  W1 is [256,1024]
__global__ void wprep1t(const float* __restrict__ Wl, const float* __restrict__ Wr,
                        unsigned short* __restrict__ Bh, unsigned short* __restrict__ Bl) {
    int idx = blockIdx.x * 256 + threadIdx.x;   // 524288
    int n = idx & 511, k = (idx >> 9) & 255, h = idx >> 17;
    const float* W = (n < 256) ? Wl : Wr;
    float w = W[(size_t)k * 1024 + h * 256 + (n & 255)];
    size_t dst = tiled_idx(h, n, k);
    unsigned u = __float_as_uint(w);
    Bh[dst] = (unsigned short)(u >> 16);                       // trunc hi
    Bl[dst] = f2bf(w - __uint_as_float(u & 0xFFFF0000u));      // RNE lo
}
// L2: element (h,n,k) = (n<256 ? Wl2 : Wr2)[h*256 + k][n&255];  W2 is [1024,256]
__global__ void wprep2t(const float* __restrict__ Wl, const float* __restrict__ Wr,
                        unsigned short* __restrict__ Bh, unsigned short* __restrict__ Bl) {
    int idx = blockIdx.x * 256 + threadIdx.x;
    int n = idx & 511, k = (idx >> 9) & 255, h = idx >> 17;
    const float* W = (n < 256) ? Wl : Wr;
    float w = W[(size_t)(h * 256 + k) * 256 + (n & 255)];
    size_t dst = tiled_idx(h, n, k);
    unsigned u = __float_as_uint(w);
    Bh[dst] = (unsigned short)(u >> 16);
    Bl[dst] = f2bf(w - __uint_as_float(u & 0xFFFF0000u));
}

// ================= B-stationary split-bf16 MFMA GEMM =================
// C[M,512] (cols sliced by 64) = A[M,256] @ B^T (+bias / +=), 3 passes
// (AhBh + AlBh + AhBl). Block = 256 thr = 4 waves; block covers 256 rows x 64 cols;
// wave w owns rows [m0+64w, +64) (4 m-frags), all 4 n-frags of the slice.
// B slice (hi+lo, 64 KB) loaded to LDS ONCE per block; K-loop barrier-free.
// A: AF32 -> x f32 split in-reg; else h1 hi/lo shorts from xlr rows
// (hi at shorts row*1024+512+k, lo at +256). C interleaved ldc=512.
template<bool AF32>
__launch_bounds__(256, 2)
__global__ void gemm_bstat(const float* __restrict__ Af,
                           const unsigned short* __restrict__ A2,
                           const unsigned short* __restrict__ Bh,
                           const unsigned short* __restrict__ Bl,
                           const float* __restrict__ bL, const float* __restrict__ bR,
                           float* __restrict__ C, int M, int accum) {
    __shared__ unsigned short Bs[2][16384];   // [hi|lo][4nt x 8kt x 512] = 64 KB
    const int tid = threadIdx.x;
    const int lane = tid & 63, w = tid >> 6;
    const int slice = blockIdx.x;             // cols [slice*64, +64)
    const int m0 = blockIdx.y * 256;
    const int r15 = lane & 15, kq = lane >> 4;

    // ---- fill B LDS: two 32 KB linear copies ----
    {
        const uint4* gh = (const uint4*)(Bh + (size_t)slice * 16384);
        const uint4* gl = (const uint4*)(Bl + (size_t)slice * 16384);
        uint4* lh = (uint4*)&Bs[0][0];
        uint4* ll = (uint4*)&Bs[1][0];
#pragma unroll
        for (int i = 0; i < 8; ++i) {         // 2048 uint4 per plane
            lh[i * 256 + tid] = gh[i * 256 + tid];
            ll[i * 256 + tid] = gl[i * 256 + tid];
        }
    }
    __syncthreads();

    f32x4 acc[4][4];
#pragma unroll
    for (int m = 0; m < 4; ++m)
#pragma unroll
        for (int n = 0; n < 4; ++n) acc[m][n] = (f32x4){0.f, 0.f, 0.f, 0.f};

    for (int kt = 0; kt < 8; ++kt) {
        bf16x8 ah[4], al[4];
        if (AF32) {
#pragma unroll
            for (int m = 0; m < 4; ++m) {
                int row = m0 + w * 64 + m * 16 + r15;
                row = row < M ? row : M - 1;
                const float* xp = Af + (size_t)row * 256 + kt * 32 + kq * 8;
                float vv[8];
                *(float4*)&vv[0] = *(const float4*)xp;
                *(float4*)&vv[4] = *(const float4*)(xp + 4);
                U8 uh, ul;
#pragma unroll
                for (int j = 0; j < 4; ++j) {
                    float a0 = vv[2 * j], a1 = vv[2 * j + 1];
                    unsigned u0 = __float_as_uint(a0), u1 = __float_as_uint(a1);
                    uh.w[j] = (u0 >> 16) | (u1 & 0xFFFF0000u);
                    float l0 = a0 - __uint_as_float(u0 & 0xFFFF0000u);
                    float l1 = a1 - __uint_as_float(u1 & 0xFFFF0000u);
                    ul.w[j] = (unsigned)f2bf(l0) | ((unsigned)f2bf(l1) << 16);
                }
                ah[m] = uh.v; al[m] = ul.v;
            }
        } else {
#pragma unroll
            for (int m = 0; m < 4; ++m) {
                int row = m0 + w * 64 + m * 16 + r15;
                row = row < M ? row : M - 1;
                const unsigned short* ap = A2 + (size_t)row * 1024 + 512 + kt * 32 + kq * 8;
                ah[m] = *(const bf16x8*)ap;
                al[m] = *(const bf16x8*)(ap + 256);
            }
        }
#pragma unroll
        for (int n = 0; n < 4; ++n) {
            const int bo = (n * 8 + kt) * 512 + lane * 8;
            bf16x8 bh = *(const bf16x8*)&Bs[0][bo];
            bf16x8 bl = *(const bf16x8*)&Bs[1][bo];
#pragma unroll
            for (int m = 0; m < 4; ++m) {
                acc[m][n] = __builtin_amdgcn_mfma_f32_16x16x32_bf16(ah[m], bh, acc[m][n], 0, 0, 0);
                acc[m][n] = __builtin_amdgcn_mfma_f32_16x16x32_bf16(al[m], bh, acc[m][n], 0, 0, 0);
                acc[m][n] = __builtin_amdgcn_mfma_f32_16x16x32_bf16(ah[m], bl, acc[m][n], 0, 0, 0);
            }
        }
    }
    // ---- epilogue: C/D layout col=lane&15, row=(lane>>4)*4+reg (verified r4-7) ----
#pragma unroll
    for (int n = 0; n < 4; ++n) {
        int gcol = slice * 64 + n * 16 + r15;
        float bv = accum ? 0.f : (gcol < 256 ? bL[gcol] : bR[gcol - 256]);
#pragma unroll
        for (int m = 0; m < 4; ++m) {
#pragma unroll
            for (int r = 0; r < 4; ++r) {
                int grow = m0 + w * 64 + m * 16 + kq * 4 + r;
                if (grow < M) {
                    size_t o = (size_t)grow * 512 + gcol;
                    C[o] = (accum ? C[o] : 0.f) + acc[m][n][r] + bv;
                }
            }
        }
    }
}

// ================= CSR build over dst (verified round 5/6) =================
__global__ void csr_count(const int* __restrict__ ei, int* __restrict__ cnt) {
    int e = blockIdx.x * 256 + threadIdx.x;
    if (e < NE) atomicAdd(&cnt[ei[NE + e]], 1);
}
__launch_bounds__(1024)
__global__ void csr_offsets(const int* __restrict__ cnt, int* __restrict__ off,
                            int* __restrict__ cursor) {
    __shared__ int s[1024];
    const int t = threadIdx.x;
    const int PER = 49;
    const int base = t * PER;
    int sum = 0;
    for (int i = 0; i < PER; ++i) {
        int idx = base + i;
        if (idx < NN) sum += cnt[idx];
    }
    s[t] = sum;
    __syncthreads();
    for (int d = 1; d < 1024; d <<= 1) {
        int v = (t >= d) ? s[t - d] : 0;
        __syncthreads();
        s[t] += v;
        __syncthreads();
    }
    int run = s[t] - sum;
    for (int i = 0; i < PER; ++i) {
        int idx = base + i;
        if (idx < NN) {
            off[idx] = run;
            cursor[idx] = run;
            run += cnt[idx];
            if (idx == NN - 1) off[NN] = run;
        }
    }
}
__global__ void csr_fill(const int* __restrict__ ei, int* __restrict__ cursor,
                         int* __restrict__ eidl) {
    int e = blockIdx.x * 256 + threadIdx.x;
    if (e < NE) {
        int d = ei[NE + e];
        int p = atomicAdd(&cursor[d], 1);
        eidl[p] = e;
    }
}

// ---------- per-edge logit partial (verbatim round 6) ----------
__device__ __forceinline__ float edge_part(const float4& l, const float4& r,
                                           const float* ev, const float (*rW)[4],
                                           const float4& attv) {
    const float* lp = &l.x; const float* rp = &r.x; const float* ap = &attv.x;
    float part = 0.f;
#pragma unroll
    for (int j = 0; j < 4; ++j) {
        float ecf = 0.f;
#pragma unroll
        for (int d = 0; d < 12; ++d) ecf = fmaf(ev[d], rW[d][j], ecf);
        float mv = lp[j] + rp[j] + ecf;
        mv = mv > 0.f ? mv : SLOPE * mv;
        part = fmaf(mv, ap[j], part);
    }
    return part;
}

// ---------- fused node pass (verbatim round 6): 4 nodes/block, own-row write ----------
template<int NHEADS, bool OUTSPLIT>
__launch_bounds__(256)
__global__ void node_fused(float* __restrict__ xlr,
                           const int* __restrict__ off, const int* __restrict__ eidl,
                           const int* __restrict__ ei, const float* __restrict__ ea,
                           const float* __restrict__ We, int ldwe,
                           const float* __restrict__ att,
                           const float* __restrict__ bias, const float* __restrict__ gam,
                           const float* __restrict__ bet, const float* __restrict__ mu,
                           const float* __restrict__ var) {
    const int n = blockIdx.x * 4 + (threadIdx.x >> 6);
    const int lane = threadIdx.x & 63;
    const int cf = lane * 4;
    float rW[12][4];
#pragma unroll
    for (int d = 0; d < 12; ++d) {
        float4 w = *(const float4*)&We[(size_t)d * ldwe + cf];
        rW[d][0] = w.x; rW[d][1] = w.y; rW[d][2] = w.z; rW[d][3] = w.w;
    }
    const float4 attv = *(const float4*)&att[cf];
    float* xrow = xlr + (size_t)n * 512;
    const float4 xr4 = *(const float4*)(xrow + 256 + cf);
    float acc[4] = {0.f, 0.f, 0.f, 0.f};
    float den = 0.f;
    const int beg = off[n], end = off[n + 1];
    constexpr int RED = 64 / NHEADS;
    int k = beg;
    for (; k + 2 <= end; k += 2) {
        int e0 = eidl[k], e1 = eidl[k + 1];
        int s0 = ei[e0], s1 = ei[e1];
        float ev0[12], ev1[12];
        const float2* p0 = (const float2*)(ea + (size_t)e0 * 12);
        const float2* p1 = (const float2*)(ea + (size_t)e1 * 12);
#pragma unroll
        for (int d = 0; d < 6; ++d) {
            float2 a = p0[d], b = p1[d];
            ev0[2 * d] = a.x; ev0[2 * d + 1] = a.y;
            ev1[2 * d] = b.x; ev1[2 * d + 1] = b.y;
        }
        float4 l0 = *(const float4*)(xlr + (size_t)s0 * 512 + cf);
        float4 l1 = *(const float4*)(xlr + (size_t)s1 * 512 + cf);
        float pa = edge_part(l0, xr4, ev0, rW, attv);
        float pb = edge_part(l1, xr4, ev1, rW, attv);
#pragma unroll
        for (int o = RED / 2; o > 0; o >>= 1) {
            pa += __shfl_xor(pa, o);
            pb += __shfl_xor(pb, o);
        }
        float ex0 = __expf(pa), ex1 = __expf(pb);
        den += ex0 + ex1;
        const float* lp0 = &l0.x; const float* lp1 = &l1.x;
#pragma unroll
        for (int j = 0; j < 4; ++j)
            acc[j] = fmaf(ex0, lp0[j], fmaf(ex1, lp1[j], acc[j]));
    }
    if (k < end) {
        int e0 = eidl[k];
        int s0 = ei[e0];
        float ev0[12];
        const float2* p0 = (const float2*)(ea + (size_t)e0 * 12);
#pragma unroll
        for (int d = 0; d < 6; ++d) {
            float2 a = p0[d];
            ev0[2 * d] = a.x; ev0[2 * d + 1] = a.y;
        }
        float4 l0 = *(const float4*)(xlr + (size_t)s0 * 512 + cf);
        float pa = edge_part(l0, xr4, ev0, rW, attv);
#pragma unroll
        for (int o = RED / 2; o > 0; o >>= 1) pa += __shfl_xor(pa, o);
        float ex0 = __expf(pa);
        den += ex0;
        const float* lp0 = &l0.x;
#pragma unroll
        for (int j = 0; j < 4; ++j) acc[j] = fmaf(ex0, lp0[j], acc[j]);
    }
    const float inv = 1.f / (den + 1e-16f);
    float o[4];
#pragma unroll
    for (int j = 0; j < 4; ++j) {
        int c = cf + j;
        float t = fmaxf(acc[j] * inv + bias[c], 0.f);
        o[j] = (t - mu[c]) * rsqrtf(var[c] + EPSBN) * gam[c] + bet[c];
    }
    if (OUTSPLIT) {   // h1 hi at shorts [512,768) of row, lo at [768,1024)
        unsigned short* oh = (unsigned short*)(xrow + 256);
        ushort4 hv, lv;
        unsigned short h0 = f2bf(o[0]), h1 = f2bf(o[1]), h2 = f2bf(o[2]), h3 = f2bf(o[3]);
        hv.x = h0; hv.y = h1; hv.z = h2; hv.w = h3;
        lv.x = f2bf(o[0] - bf2f(h0)); lv.y = f2bf(o[1] - bf2f(h1));
        lv.z = f2bf(o[2] - bf2f(h2)); lv.w = f2bf(o[3] - bf2f(h3));
        *(ushort4*)(oh + cf) = hv;
        *(ushort4*)(oh + 256 + cf) = lv;
    } else {
        *(float4*)(xrow + 256 + cf) = make_float4(o[0], o[1], o[2], o[3]);
    }
}

// ================= head MLP =================
__launch_bounds__(64)
__global__ void head_mlp(const float* __restrict__ h2, const int* __restrict__ n_nodes,
                         const float* __restrict__ Wf1, const float* __restrict__ bf1,
                         const float* __restrict__ Wf2, const float* __restrict__ bf2,
                         float* __restrict__ out) {
    const int g = blockIdx.x;
    const int t = threadIdx.x;
    int acc = 0;
    for (int i = t; i <= g; i += 64) acc += n_nodes[i];
#pragma unroll
    for (int off = 32; off > 0; off >>= 1) acc += __shfl_xor(acc, off);
    const int node = acc - 1;
    __shared__ float row[256];
    for (int i = t; i < 256; i += 64) row[i] = h2[(size_t)node * 512 + 256 + i];
    __syncthreads();
    float hid = bf1[t];
    for (int k = 0; k < 256; ++k) hid = fmaf(row[k], Wf1[k * 64 + t], hid);
    hid = fmaxf(hid, 0.f);
    float p = hid * Wf2[t];
#pragma unroll
    for (int off = 32; off > 0; off >>= 1) p += __shfl_xor(p, off);
    if (t == 0) out[g] = p + bf2[0];
}

extern "C" void kernel_launch(void* const* d_in, const int* in_sizes, int n_in,
                              void* d_out, int out_size, void* d_ws, size_t ws_size,
                              hipStream_t stream) {
    const float* x   = (const float*)d_in[0];
    const int*   ei  = (const int*)d_in[1];
    const float* ea  = (const float*)d_in[2];
    const int*   nnd = (const int*)d_in[3];
    const float* Wl1 = (const float*)d_in[4];
    const float* bl1 = (const float*)d_in[5];
    const float* Wr1 = (const float*)d_in[6];
    const float* br1 = (const float*)d_in[7];
    const float* We1 = (const float*)d_in[8];
    const float* att1= (const float*)d_in[9];
    const float* b1  = (const float*)d_in[10];
    const float* g1  = (const float*)d_in[11];
    const float* be1 = (const float*)d_in[12];
    const float* m1  = (const float*)d_in[13];
    const float* v1  = (const float*)d_in[14];
    const float* Wl2 = (const float*)d_in[15];
    const float* bl2 = (const float*)d_in[16];
    const float* Wr2 = (const float*)d_in[17];
    const float* br2 = (const float*)d_in[18];
    const float* We2 = (const float*)d_in[19];
    const float* att2= (const float*)d_in[20];
    const float* b2  = (const float*)d_in[21];
    const float* g2  = (const float*)d_in[22];
    const float* be2 = (const float*)d_in[23];
    const float* m2  = (const float*)d_in[24];
    const float* v2  = (const float*)d_in[25];
    const float* Wf1 = (const float*)d_in[26];
    const float* bf1 = (const float*)d_in[27];
    const float* Wf2 = (const float*)d_in[28];
    const float* bf2 = (const float*)d_in[29];
    float* out = (float*)d_out;

    // ---- workspace (~210.3 MB; round-6 proved fit) ----
    const size_t XB = (size_t)NN * 512 * 4;       // 102.4 MB interleaved panel
    const size_t WPB = (size_t)4 * 512 * 256 * 2; // 1 MB per split plane (4 heads)
    char* ws = (char*)d_ws;
    size_t off = 0;
    float* xlr  = (float*)(ws + off); off += XB;  // [xl f32 | xr f32 -> h1 hi/lo]
    float* xlr2 = (float*)(ws + off); off += XB;
    unsigned short* B1h = (unsigned short*)(ws + off); off += WPB;
    unsigned short* B1l = (unsigned short*)(ws + off); off += WPB;
    unsigned short* B2h = (unsigned short*)(ws + off); off += WPB;
    unsigned short* B2l = (unsigned short*)(ws + off); off += WPB;
    int* cnt    = (int*)(ws + off); off += (size_t)NN * 4;
    int* csroff = (int*)(ws + off); off += ((size_t)(NN + 1) * 4 + 15) & ~15ull;
    int* cursor = (int*)(ws + off); off += (size_t)NN * 4;
    int* eidl   = (int*)(ws + off); off += (size_t)NE * 4;
    if (ws_size < off) {
        fill_val<<<(out_size + 255) / 256, 256, 0, stream>>>(out, out_size, 1e30f);
        return;
    }

    // ---- CSR build (once) ----
    hipMemsetAsync(cnt, 0, (size_t)NN * 4, stream);
    csr_count<<<(NE + 255) / 256, 256, 0, stream>>>(ei, cnt);
    csr_offsets<<<1, 1024, 0, stream>>>(cnt, csroff, cursor);
    csr_fill<<<(NE + 255) / 256, 256, 0, stream>>>(ei, cursor, eidl);

    // ---- weight prep ----
    wprep1t<<<2048, 256, 0, stream>>>(Wl1, Wr1, B1h, B1l);
    wprep2t<<<2048, 256, 0, stream>>>(Wl2, Wr2, B2h, B2l);

    const dim3 gg(8, (NN + 255) / 256);   // 8 col-slices x 196 row-tiles
    const int nodeBlocks = NN / 4;        // 12500

    for (int h = 0; h < NH; ++h) {
        // xlr = [x@Wl1_h + bl | x@Wr1_h + br]
        gemm_bstat<true><<<gg, 256, 0, stream>>>(
            x, nullptr, B1h + (size_t)h * 131072, B1l + (size_t)h * 131072,
            bl1 + h * 256, br1 + h * 256, xlr, NN, 0);
        // softmax-aggregate + bias/relu/bn -> h1_h split bf16 over own row's xr half
        node_fused<1, true><<<nodeBlocks, 256, 0, stream>>>(
            xlr, csroff, eidl, ei, ea, We1 + h * 256, 1024, att1 + h * 256,
            b1 + h * 256, g1 + h * 256, be1 + h * 256, m1 + h * 256, v1 + h * 256);
        // xlr2 (+)= [h1_h@Wl2_chunk | h1_h@Wr2_chunk]
        gemm_bstat<false><<<gg, 256, 0, stream>>>(
            nullptr, (const unsigned short*)xlr, B2h + (size_t)h * 131072,
            B2l + (size_t)h * 131072, bl2, br2, xlr2, NN, h > 0 ? 1 : 0);
    }

    // layer-2 attention (4 heads), f32 in-place over xr half of xlr2
    node_fused<4, false><<<nodeBlocks, 256, 0, stream>>>(
        xlr2, csroff, eidl, ei, ea, We2, 256, att2, b2, g2, be2, m2, v2);

    head_mlp<<<NG, 64, 0, stream>>>(xlr2, nnd, Wf1, bf1, Wf2, bf2, out);
}